// Round 1
// baseline (1354.790 us; speedup 1.0000x reference)
//
#include <hip/hip_runtime.h>
#include <hip/hip_bf16.h>

typedef __attribute__((ext_vector_type(4))) float f32x4;
typedef __attribute__((ext_vector_type(8))) short s16x8;

#define SEQ 2048
#define DM  2048
#define NH  16
#define HD  128
#define NB  4

__device__ __forceinline__ unsigned short f2b(float f){
  unsigned int u = __builtin_bit_cast(unsigned int, f);
  u += 0x7fffu + ((u >> 16) & 1u);
  return (unsigned short)(u >> 16);
}
__device__ __forceinline__ float b2f(unsigned short h){
  unsigned int u = ((unsigned int)h) << 16;
  return __builtin_bit_cast(float, u);
}
__device__ __forceinline__ f32x4 mfma16(s16x8 a, s16x8 b, f32x4 c){
  return __builtin_amdgcn_mfma_f32_16x16x32_bf16(a, b, c, 0, 0, 0);
}

// ---------------------------------------------------------------------------
// GEMM: C[M][N] = A[M][K] * W[N][K]^T   (bf16 MFMA, K=2048)
// MODE 0: A = x (f32). N=6144 fused [Wq|Wk|Wv]. Q,K cols -> qkpre bf16
//         (8192 x 4096). V cols -> d_out v (f32, B,H,S,hd) + vt bf16 (B,H,hd,S).
// MODE 1: A = attn_out (bf16), W = w_o, C -> outf (f32, 8192 x 2048).
// ---------------------------------------------------------------------------
template<int MODE>
__global__ __launch_bounds__(256)
void gemm_kernel(const void* __restrict__ Ap, const float* __restrict__ W0,
                 const float* __restrict__ W1, const float* __restrict__ W2,
                 unsigned short* __restrict__ qkpre, float* __restrict__ voutf,
                 unsigned short* __restrict__ vt, float* __restrict__ outf)
{
  constexpr int K = 2048;
  const int tid  = threadIdx.x;
  const int lane = tid & 63;
  const int w    = tid >> 6;
  const int wr   = w >> 1, wc = w & 1;
  const int m0   = blockIdx.x * 128;
  const int n0   = blockIdx.y * 128;

  __shared__ unsigned short Alds[128 * 64];  // row = 128B, XOR-swizzled 16B slots
  __shared__ unsigned short Blds[128 * 64];

  const float* Bsrc; int bn0;
  if (MODE == 0){
    if (n0 < 2048)      { Bsrc = W0; bn0 = n0; }
    else if (n0 < 4096) { Bsrc = W1; bn0 = n0 - 2048; }
    else                { Bsrc = W2; bn0 = n0 - 4096; }
  } else { Bsrc = W0; bn0 = n0; }

  f32x4 acc[4][4] = {};

  const int srow  = tid >> 1;   // 0..127
  const int shalf = tid & 1;    // 0..1  (32 elements each)

  for (int k0 = 0; k0 < K; k0 += 64){
    __syncthreads();
    // ---- stage A ----
    if (MODE == 0){
      const float* src = (const float*)Ap + (size_t)(m0 + srow) * K + k0 + shalf * 32;
      #pragma unroll
      for (int q = 0; q < 4; q++){
        float4 fa = ((const float4*)src)[2*q];
        float4 fb = ((const float4*)src)[2*q+1];
        s16x8 v;
        v[0]=(short)f2b(fa.x); v[1]=(short)f2b(fa.y); v[2]=(short)f2b(fa.z); v[3]=(short)f2b(fa.w);
        v[4]=(short)f2b(fb.x); v[5]=(short)f2b(fb.y); v[6]=(short)f2b(fb.z); v[7]=(short)f2b(fb.w);
        int byt = (shalf*64 + q*16) ^ ((srow & 7) << 4);
        *(s16x8*)((char*)Alds + srow*128 + byt) = v;
      }
    } else {
      const unsigned short* src = (const unsigned short*)Ap + (size_t)(m0 + srow) * K + k0 + shalf * 32;
      #pragma unroll
      for (int q = 0; q < 4; q++){
        s16x8 v = ((const s16x8*)src)[q];
        int byt = (shalf*64 + q*16) ^ ((srow & 7) << 4);
        *(s16x8*)((char*)Alds + srow*128 + byt) = v;
      }
    }
    // ---- stage B (always f32 weights) ----
    {
      const float* src = Bsrc + (size_t)(bn0 + srow) * K + k0 + shalf * 32;
      #pragma unroll
      for (int q = 0; q < 4; q++){
        float4 fa = ((const float4*)src)[2*q];
        float4 fb = ((const float4*)src)[2*q+1];
        s16x8 v;
        v[0]=(short)f2b(fa.x); v[1]=(short)f2b(fa.y); v[2]=(short)f2b(fa.z); v[3]=(short)f2b(fa.w);
        v[4]=(short)f2b(fb.x); v[5]=(short)f2b(fb.y); v[6]=(short)f2b(fb.z); v[7]=(short)f2b(fb.w);
        int byt = (shalf*64 + q*16) ^ ((srow & 7) << 4);
        *(s16x8*)((char*)Blds + srow*128 + byt) = v;
      }
    }
    __syncthreads();
    // ---- compute: 2 K=32 sub-steps, 4x4 16x16 frags per wave ----
    #pragma unroll
    for (int ks = 0; ks < 2; ks++){
      s16x8 af[4], bfr[4];
      const int kb = ks*64 + ((lane >> 4) << 4);   // byte offset within row
      #pragma unroll
      for (int i = 0; i < 4; i++){
        int r = wr*64 + i*16 + (lane & 15);
        af[i] = *(const s16x8*)((const char*)Alds + r*128 + (kb ^ ((r & 7) << 4)));
      }
      #pragma unroll
      for (int j = 0; j < 4; j++){
        int r = wc*64 + j*16 + (lane & 15);
        bfr[j] = *(const s16x8*)((const char*)Blds + r*128 + (kb ^ ((r & 7) << 4)));
      }
      #pragma unroll
      for (int i = 0; i < 4; i++)
        #pragma unroll
        for (int j = 0; j < 4; j++)
          acc[i][j] = mfma16(af[i], bfr[j], acc[i][j]);
    }
  }

  // ---- epilogue: C/D layout col=lane&15, row=(lane>>4)*4+reg ----
  const int col = lane & 15;
  const int rq  = (lane >> 4) << 2;
  #pragma unroll
  for (int i = 0; i < 4; i++){
    #pragma unroll
    for (int j = 0; j < 4; j++){
      #pragma unroll
      for (int r = 0; r < 4; r++){
        float v = acc[i][j][r];
        int m = m0 + wr*64 + i*16 + rq + r;
        int n = n0 + wc*64 + j*16 + col;
        if (MODE == 0){
          if (n0 < 4096){
            qkpre[(size_t)m * 4096 + n] = f2b(v);
          } else {
            int vc = n - 4096;
            int h = vc >> 7, d = vc & 127;
            int b = m >> 11, s2 = m & 2047;
            voutf[(size_t)((b*NH + h)*SEQ + s2) * HD + d] = v;
            vt[(size_t)((b*NH + h)*HD + d) * SEQ + s2]    = f2b(v);
          }
        } else {
          outf[(size_t)m * DM + n] = v;
        }
      }
    }
  }
}

// ---------------------------------------------------------------------------
// RoPE over full D=2048: pairs (2i,2i+1) -> out cols i and i+1024.
// Writes Q,K bf16 in (B,H,S,hd) + K f32 to d_out k region.
// ---------------------------------------------------------------------------
__global__ __launch_bounds__(256)
void rope_kernel(const unsigned short* __restrict__ qkpre,
                 unsigned short* __restrict__ qr,
                 unsigned short* __restrict__ kr,
                 float* __restrict__ koutf,
                 const int* __restrict__ start_pos)
{
  const int bs = blockIdx.x;            // 0..8191
  const int b = bs >> 11, s = bs & 2047;
  const float pos = (float)(start_pos[0] + s);
  const unsigned short* qrow = qkpre + (size_t)bs * 4096;
  const unsigned short* krow = qrow + 2048;
  const int t = threadIdx.x;
  #pragma unroll
  for (int ii = 0; ii < 4; ii++){
    int i = t + ii * 256;               // 0..1023 (frequency index)
    float f = exp2f(-(float)i * (13.287712379549449f / 1024.0f));
    float ang = pos * f;
    float sn, cs;
    __sincosf(ang, &sn, &cs);
    float q1 = b2f(qrow[2*i]), q2 = b2f(qrow[2*i+1]);
    float k1 = b2f(krow[2*i]), k2 = b2f(krow[2*i+1]);
    float qo1 = q1*cs - q2*sn, qo2 = q1*sn + q2*cs;
    float ko1 = k1*cs - k2*sn, ko2 = k1*sn + k2*cs;
    int j2 = i + 1024;
    size_t o1 = ((size_t)(b*NH + (i  >> 7)) * SEQ + s) * HD + (i  & 127);
    size_t o2 = ((size_t)(b*NH + (j2 >> 7)) * SEQ + s) * HD + (j2 & 127);
    qr[o1] = f2b(qo1); qr[o2] = f2b(qo2);
    kr[o1] = f2b(ko1); kr[o2] = f2b(ko2);
    koutf[o1] = ko1;   koutf[o2] = ko2;
  }
}

// ---------------------------------------------------------------------------
// Causal flash attention. Block = (64 q-rows) x one (b,h); 4 waves x 16 rows.
// KV tiles of 32 staged in swizzled LDS. P via per-wave 1KB LDS round-trip.
// ---------------------------------------------------------------------------
__global__ __launch_bounds__(256)
void attn_kernel(const unsigned short* __restrict__ qr,
                 const unsigned short* __restrict__ kr,
                 const unsigned short* __restrict__ vt,
                 unsigned short* __restrict__ attnout)
{
  const int qb   = blockIdx.x;          // 0..31
  const int bh   = blockIdx.y;          // 0..63
  const int tid  = threadIdx.x;
  const int lane = tid & 63;
  const int w    = tid >> 6;
  const int q0w  = qb*64 + w*16;

  __shared__ unsigned short Klds[32 * 128];   // rows 256B, swz (row&15)<<4
  __shared__ unsigned short Vlds[128 * 64];   // rows 128B (32 cols used), swz (row&7)<<4
  __shared__ unsigned short Plds[4][16 * 32]; // per-wave P tile, linear

  // Q fragments (a-operand): lane reads row q0w+(lane&15), k-chunk (lane>>4)*8
  s16x8 qf[4];
  const unsigned short* qbase = qr + ((size_t)bh*SEQ + q0w + (lane & 15)) * HD + ((lane >> 4) * 8);
  #pragma unroll
  for (int c = 0; c < 4; c++) qf[c] = *(const s16x8*)(qbase + c*32);

  f32x4 o[8] = {};
  float mrow[4] = {-1e30f,-1e30f,-1e30f,-1e30f};
  float lrow[4] = {0.f,0.f,0.f,0.f};

  const int ntiles = 2*qb + 2;
  for (int t = 0; t < ntiles; t++){
    const int kv0 = t * 32;
    __syncthreads();
    { // stage K tile (32 x 128 bf16)
      int r = tid >> 3, sb = (tid & 7) * 32;
      const unsigned short* src = kr + ((size_t)bh*SEQ + kv0 + r) * HD + sb/2;
      s16x8 v0 = ((const s16x8*)src)[0];
      s16x8 v1 = ((const s16x8*)src)[1];
      *(s16x8*)((char*)Klds + r*256 + ( sb        ^ ((r & 15) << 4))) = v0;
      *(s16x8*)((char*)Klds + r*256 + ((sb + 16)  ^ ((r & 15) << 4))) = v1;
    }
    { // stage V^T tile (128 x 32 bf16)
      int d = tid >> 1, hb = (tid & 1) * 32;
      const unsigned short* src = vt + ((size_t)bh*HD + d) * SEQ + kv0 + hb/2;
      s16x8 v0 = ((const s16x8*)src)[0];
      s16x8 v1 = ((const s16x8*)src)[1];
      *(s16x8*)((char*)Vlds + d*128 + ( hb        ^ ((d & 7) << 4))) = v0;
      *(s16x8*)((char*)Vlds + d*128 + ((hb + 16)  ^ ((d & 7) << 4))) = v1;
    }
    __syncthreads();

    // S = Q K^T  (16 x 32 as two 16x16 D-tiles)
    f32x4 st[2];
    st[0] = (f32x4){0.f,0.f,0.f,0.f};
    st[1] = (f32x4){0.f,0.f,0.f,0.f};
    #pragma unroll
    for (int n2 = 0; n2 < 2; n2++){
      int krw = n2*16 + (lane & 15);
      #pragma unroll
      for (int c = 0; c < 4; c++){
        s16x8 kf = *(const s16x8*)((const char*)Klds + krw*256 +
                     ((c*64 + ((lane >> 4) << 4)) ^ ((krw & 15) << 4)));
        st[n2] = mfma16(qf[c], kf, st[n2]);
      }
    }
    const float sc = 0.08838834764831845f;  // 1/sqrt(128)
    float pm[2][4];
    #pragma unroll
    for (int n2 = 0; n2 < 2; n2++)
      #pragma unroll
      for (int r = 0; r < 4; r++){
        float v = st[n2][r] * sc;
        int qrow2 = q0w + ((lane >> 4) << 2) + r;
        int kvc   = kv0 + n2*16 + (lane & 15);
        pm[n2][r] = (kvc > qrow2) ? -1e30f : v;
      }
    // online softmax (row lives across the 16 lanes of each quarter-wave)
    float mt[4], mnew[4], al[4], rs[4];
    #pragma unroll
    for (int r = 0; r < 4; r++) mt[r] = fmaxf(pm[0][r], pm[1][r]);
    #pragma unroll
    for (int mk = 1; mk < 16; mk <<= 1)
      #pragma unroll
      for (int r = 0; r < 4; r++) mt[r] = fmaxf(mt[r], __shfl_xor(mt[r], mk));
    #pragma unroll
    for (int r = 0; r < 4; r++){
      mnew[r] = fmaxf(mrow[r], mt[r]);
      al[r]   = __expf(mrow[r] - mnew[r]);
    }
    unsigned short* pw = &Plds[w][0];
    #pragma unroll
    for (int r = 0; r < 4; r++){
      float p0 = __expf(pm[0][r] - mnew[r]);
      float p1 = __expf(pm[1][r] - mnew[r]);
      rs[r] = p0 + p1;
      int qlr = ((lane >> 4) << 2) + r;
      pw[qlr*32 +      (lane & 15)] = f2b(p0);
      pw[qlr*32 + 16 + (lane & 15)] = f2b(p1);
    }
    #pragma unroll
    for (int mk = 1; mk < 16; mk <<= 1)
      #pragma unroll
      for (int r = 0; r < 4; r++) rs[r] += __shfl_xor(rs[r], mk);
    #pragma unroll
    for (int r = 0; r < 4; r++){
      lrow[r] = lrow[r]*al[r] + rs[r];
      mrow[r] = mnew[r];
    }
    #pragma unroll
    for (int c = 0; c < 8; c++)
      #pragma unroll
      for (int r = 0; r < 4; r++) o[c][r] *= al[r];

    asm volatile("s_waitcnt lgkmcnt(0)" ::: "memory");
    // P a-fragment: lane reads P[lane&15][(lane>>4)*8 ..+7]
    s16x8 pa = *(const s16x8*)((const char*)pw + (lane & 15)*64 + ((lane >> 4) << 4));
    // O += P V   (8 d-chunks of 16)
    #pragma unroll
    for (int c = 0; c < 8; c++){
      int d = c*16 + (lane & 15);
      s16x8 vf = *(const s16x8*)((const char*)Vlds + d*128 +
                   ((((lane >> 4) << 4)) ^ ((d & 7) << 4)));
      o[c] = mfma16(pa, vf, o[c]);
    }
  }

  // epilogue -> attn_out (B,S,D) bf16
  const int b = bh >> 4, h = bh & 15;
  #pragma unroll
  for (int r = 0; r < 4; r++){
    float inv = 1.0f / lrow[r];
    int s2 = q0w + ((lane >> 4) << 2) + r;
    size_t base = ((size_t)(b*SEQ + s2)) * DM + h*HD;
    #pragma unroll
    for (int c = 0; c < 8; c++)
      attnout[base + c*16 + (lane & 15)] = f2b(o[c][r] * inv);
  }
}

// ---------------------------------------------------------------------------
extern "C" void kernel_launch(void* const* d_in, const int* in_sizes, int n_in,
                              void* d_out, int out_size, void* d_ws, size_t ws_size,
                              hipStream_t stream)
{
  const float* x  = (const float*)d_in[0];
  const float* wq = (const float*)d_in[1];
  const float* wk = (const float*)d_in[2];
  const float* wv = (const float*)d_in[3];
  const float* wo = (const float*)d_in[4];
  const int*   sp = (const int*)d_in[5];

  float* out  = (float*)d_out;            // (B,S,D) f32
  float* kout = out + 16777216;           // (B,H,S,hd) f32
  float* vout = out + 33554432;           // (B,H,S,hd) f32

  char* ws = (char*)d_ws;
  unsigned short* qkpre   = (unsigned short*)ws;                  // 8192x4096 bf16 (67.1MB)
  unsigned short* qr      = (unsigned short*)(ws + 67108864);     // (B,H,S,hd) bf16
  unsigned short* kr      = (unsigned short*)(ws + 100663296);    // (B,H,S,hd) bf16
  unsigned short* vt      = (unsigned short*)(ws + 134217728);    // (B,H,hd,S) bf16
  unsigned short* attnout = (unsigned short*)ws;                  // alias qkpre (done after rope)

  // 1) fused QKV GEMM
  gemm_kernel<0><<<dim3(64, 48), 256, 0, stream>>>(x, wq, wk, wv, qkpre, vout, vt, nullptr);
  // 2) RoPE on Q,K (+ K f32 output)
  rope_kernel<<<dim3(8192), 256, 0, stream>>>(qkpre, qr, kr, kout, sp);
  // 3) causal flash attention
  attn_kernel<<<dim3(32, 64), 256, 0, stream>>>(qr, kr, vt, attnout);
  // 4) output GEMM
  gemm_kernel<1><<<dim3(64, 16), 256, 0, stream>>>(attnout, wo, nullptr, nullptr,
                                                   nullptr, nullptr, nullptr, out);
}

// Round 3
// 854.789 us; speedup vs baseline: 1.5849x; 1.5849x over previous
//
#include <hip/hip_runtime.h>
#include <hip/hip_bf16.h>

typedef __attribute__((ext_vector_type(4))) float f32x4;
typedef __attribute__((ext_vector_type(8))) short s16x8;

#define SEQ 2048
#define DM  2048
#define NH  16
#define HD  128

__device__ __forceinline__ unsigned short f2b(float f){
  unsigned int u = __builtin_bit_cast(unsigned int, f);
  u += 0x7fffu + ((u >> 16) & 1u);
  return (unsigned short)(u >> 16);
}
__device__ __forceinline__ float b2f(unsigned short h){
  unsigned int u = ((unsigned int)h) << 16;
  return __builtin_bit_cast(float, u);
}
__device__ __forceinline__ f32x4 mfma16(s16x8 a, s16x8 b, f32x4 c){
  return __builtin_amdgcn_mfma_f32_16x16x32_bf16(a, b, c, 0, 0, 0);
}

// ---------------------------------------------------------------------------
// One-shot f32 -> bf16 conversion: x -> xb, [wq|wk|wv] -> wfused, wo -> wob.
// ---------------------------------------------------------------------------
__global__ __launch_bounds__(256)
void convert_kernel(const float* __restrict__ x,  const float* __restrict__ wq,
                    const float* __restrict__ wk, const float* __restrict__ wv,
                    const float* __restrict__ wo,
                    unsigned short* __restrict__ xb,
                    unsigned short* __restrict__ wfused,
                    unsigned short* __restrict__ wob)
{
  size_t e = ((size_t)blockIdx.x * 256 + threadIdx.x) * 8;
  const float* src; unsigned short* dst;
  if (e < 16777216){ src = x + e; dst = xb + e; }
  else if (e < 29360128){
    size_t o = e - 16777216;
    int sel = (int)(o >> 22);
    const float* w = sel == 0 ? wq : (sel == 1 ? wk : wv);
    src = w + (o & 4194303); dst = wfused + o;
  } else {
    size_t o = e - 29360128;
    src = wo + o; dst = wob + o;
  }
  float4 a = ((const float4*)src)[0];
  float4 b = ((const float4*)src)[1];
  s16x8 v;
  v[0]=(short)f2b(a.x); v[1]=(short)f2b(a.y); v[2]=(short)f2b(a.z); v[3]=(short)f2b(a.w);
  v[4]=(short)f2b(b.x); v[5]=(short)f2b(b.y); v[6]=(short)f2b(b.z); v[7]=(short)f2b(b.w);
  *(s16x8*)dst = v;
}

// ---------------------------------------------------------------------------
// m97-structure GEMM: C[M][N] = A[M][K] * B[N][K]^T, bf16 MFMA, K=2048,
// 128x128 tile, BK=64, global_load_lds(16B) -> linear LDS, ds_read_b128.
// MODE 0: A=xb, B=wfused (6144 rows). Q/K cols: RoPE fused in epilogue ->
//         qr/kr bf16 (B,H,S,hd) + K f32 to d_out. V cols -> vout f32 + vt bf16.
// MODE 1: A=attnout bf16, B=wob -> outf f32.
// ---------------------------------------------------------------------------
template<int MODE>
__global__ __launch_bounds__(256)
void gemm_kernel(const unsigned short* __restrict__ A,
                 const unsigned short* __restrict__ B,
                 unsigned short* __restrict__ qr, unsigned short* __restrict__ kr,
                 float* __restrict__ koutf,
                 float* __restrict__ voutf, unsigned short* __restrict__ vt,
                 float* __restrict__ outf, const int* __restrict__ sp)
{
  const int tid  = threadIdx.x;
  const int lane = tid & 63;
  const int w    = tid >> 6;
  const int wr   = w >> 1, wc = w & 1;
  const int m0   = blockIdx.x * 128;
  const int n0   = blockIdx.y * 128;

  __shared__ unsigned short Alds[128 * 64];   // linear: row stride 128B
  __shared__ unsigned short Blds[128 * 64];

  f32x4 acc[4][4] = {};

  const unsigned short* Abase = A + (size_t)m0 * 2048;
  const unsigned short* Bbase = B + (size_t)n0 * 2048;
  const int rr = lane >> 3;          // 0..7
  const int cc = (lane & 7) * 8;     // element offset within 64-col chunk

  for (int k0 = 0; k0 < 2048; k0 += 64){
    __syncthreads();
    #pragma unroll
    for (int q = 0; q < 4; q++){
      int row = q*32 + w*8 + rr;
      __builtin_amdgcn_global_load_lds(
        (const __attribute__((address_space(1))) void*)(Abase + (size_t)row*2048 + k0 + cc),
        (__attribute__((address_space(3))) void*)((char*)Alds + q*4096 + w*1024),
        16, 0, 0);
      __builtin_amdgcn_global_load_lds(
        (const __attribute__((address_space(1))) void*)(Bbase + (size_t)row*2048 + k0 + cc),
        (__attribute__((address_space(3))) void*)((char*)Blds + q*4096 + w*1024),
        16, 0, 0);
    }
    __syncthreads();
    #pragma unroll
    for (int ks = 0; ks < 2; ks++){
      s16x8 af[4], bfr[4];
      const int kb = ks*64 + ((lane >> 4) << 4);   // byte offset within row
      #pragma unroll
      for (int i = 0; i < 4; i++){
        int r = wr*64 + i*16 + (lane & 15);
        af[i] = *(const s16x8*)((const char*)Alds + r*128 + kb);
      }
      #pragma unroll
      for (int j = 0; j < 4; j++){
        int r = wc*64 + j*16 + (lane & 15);
        bfr[j] = *(const s16x8*)((const char*)Blds + r*128 + kb);
      }
      #pragma unroll
      for (int i = 0; i < 4; i++)
        #pragma unroll
        for (int j = 0; j < 4; j++)
          acc[i][j] = mfma16(af[i], bfr[j], acc[i][j]);
    }
  }

  // ---- epilogue: C/D layout col=lane&15, row=(lane>>4)*4+reg ----
  const int col = lane & 15;
  const int rq  = (lane >> 4) << 2;

  if (MODE == 1){
    #pragma unroll
    for (int i = 0; i < 4; i++)
      #pragma unroll
      for (int j = 0; j < 4; j++)
        #pragma unroll
        for (int r = 0; r < 4; r++)
          outf[(size_t)(m0 + wr*64 + i*16 + rq + r) * DM + n0 + wc*64 + j*16 + col]
            = acc[i][j][r];
    return;
  }

  const int b = m0 >> 11;
  if (n0 < 4096){
    // ---- RoPE-fused Q/K epilogue ----
    const bool isK = (n0 >= 2048);
    unsigned short* dst = isK ? kr : qr;
    const int odd = lane & 1;
    const int sp0 = sp[0];
    const int nb  = n0 - (isK ? 2048 : 0);
    float fj[4];
    #pragma unroll
    for (int j = 0; j < 4; j++){
      int nn = nb + wc*64 + j*16 + col;
      fj[j] = exp2f(-(float)(nn >> 1) * (13.287712379549449f / 1024.0f));
    }
    #pragma unroll
    for (int i = 0; i < 4; i++){
      #pragma unroll
      for (int r = 0; r < 4; r++){
        int m = m0 + wr*64 + i*16 + rq + r;
        int s = m & 2047;
        float pos = (float)(sp0 + s);
        #pragma unroll
        for (int j = 0; j < 4; j++){
          float v  = acc[i][j][r];
          float vx = __shfl_xor(v, 1);
          float sn, cs;
          __sincosf(pos * fj[j], &sn, &cs);
          float x1 = odd ? vx : v;
          float x2 = odd ? v  : vx;
          float ov = odd ? (x1*sn + x2*cs) : (x1*cs - x2*sn);
          int nn = nb + wc*64 + j*16 + col;
          int c  = (nn >> 1) + (odd ? 1024 : 0);
          size_t adr = ((size_t)(b*NH + (c >> 7)) * SEQ + s) * HD + (c & 127);
          dst[adr] = f2b(ov);
          if (isK) koutf[adr] = ov;
        }
      }
    }
  } else {
    // ---- V epilogue: vout f32 (B,H,S,hd) + vt bf16 (B,H,hd,S) ----
    const int s_b = m0 & 2047;
    #pragma unroll
    for (int i = 0; i < 4; i++){
      int sb = s_b + wr*64 + i*16 + rq;
      #pragma unroll
      for (int j = 0; j < 4; j++){
        int d = (n0 - 4096) + wc*64 + j*16 + col;
        int h = d >> 7, dd = d & 127;
        size_t vbase = ((size_t)(b*NH + h) * SEQ + sb) * HD + dd;
        #pragma unroll
        for (int r = 0; r < 4; r++)
          voutf[vbase + (size_t)r * HD] = acc[i][j][r];
        ushort4 pk;
        pk.x = f2b(acc[i][j][0]); pk.y = f2b(acc[i][j][1]);
        pk.z = f2b(acc[i][j][2]); pk.w = f2b(acc[i][j][3]);
        *(ushort4*)(vt + ((size_t)(b*NH + h) * HD + dd) * SEQ + sb) = pk;
      }
    }
  }
}

// ---------------------------------------------------------------------------
// Causal flash attention. Block = (64 q-rows) x one (b,h); 4 waves x 16 rows.
// KV tiles of 32 staged in swizzled LDS. P via per-wave 1KB LDS round-trip.
// ---------------------------------------------------------------------------
__global__ __launch_bounds__(256)
void attn_kernel(const unsigned short* __restrict__ qr,
                 const unsigned short* __restrict__ kr,
                 const unsigned short* __restrict__ vt,
                 unsigned short* __restrict__ attnout)
{
  const int qb   = blockIdx.x;          // 0..31
  const int bh   = blockIdx.y;          // 0..63
  const int tid  = threadIdx.x;
  const int lane = tid & 63;
  const int w    = tid >> 6;
  const int q0w  = qb*64 + w*16;

  __shared__ unsigned short Klds[32 * 128];   // rows 256B, swz (row&15)<<4
  __shared__ unsigned short Vlds[128 * 64];   // rows 128B (32 cols used), swz (row&7)<<4
  __shared__ unsigned short Plds[4][16 * 32]; // per-wave P tile, linear

  s16x8 qf[4];
  const unsigned short* qbase = qr + ((size_t)bh*SEQ + q0w + (lane & 15)) * HD + ((lane >> 4) * 8);
  #pragma unroll
  for (int c = 0; c < 4; c++) qf[c] = *(const s16x8*)(qbase + c*32);

  f32x4 o[8] = {};
  float mrow[4] = {-1e30f,-1e30f,-1e30f,-1e30f};
  float lrow[4] = {0.f,0.f,0.f,0.f};

  const int ntiles = 2*qb + 2;
  for (int t = 0; t < ntiles; t++){
    const int kv0 = t * 32;
    __syncthreads();
    { // stage K tile (32 x 128 bf16)
      int r = tid >> 3, sb = (tid & 7) * 32;
      const unsigned short* src = kr + ((size_t)bh*SEQ + kv0 + r) * HD + sb/2;
      s16x8 v0 = ((const s16x8*)src)[0];
      s16x8 v1 = ((const s16x8*)src)[1];
      *(s16x8*)((char*)Klds + r*256 + ( sb        ^ ((r & 15) << 4))) = v0;
      *(s16x8*)((char*)Klds + r*256 + ((sb + 16)  ^ ((r & 15) << 4))) = v1;
    }
    { // stage V^T tile (128 x 32 bf16)
      int d = tid >> 1, hb = (tid & 1) * 32;
      const unsigned short* src = vt + ((size_t)bh*HD + d) * SEQ + kv0 + hb/2;
      s16x8 v0 = ((const s16x8*)src)[0];
      s16x8 v1 = ((const s16x8*)src)[1];
      *(s16x8*)((char*)Vlds + d*128 + ( hb        ^ ((d & 7) << 4))) = v0;
      *(s16x8*)((char*)Vlds + d*128 + ((hb + 16)  ^ ((d & 7) << 4))) = v1;
    }
    __syncthreads();

    // S = Q K^T  (16 x 32 as two 16x16 D-tiles)
    f32x4 st[2];
    st[0] = (f32x4){0.f,0.f,0.f,0.f};
    st[1] = (f32x4){0.f,0.f,0.f,0.f};
    #pragma unroll
    for (int n2 = 0; n2 < 2; n2++){
      int krw = n2*16 + (lane & 15);
      #pragma unroll
      for (int c = 0; c < 4; c++){
        s16x8 kf = *(const s16x8*)((const char*)Klds + krw*256 +
                     ((c*64 + ((lane >> 4) << 4)) ^ ((krw & 15) << 4)));
        st[n2] = mfma16(qf[c], kf, st[n2]);
      }
    }
    const float sc = 0.08838834764831845f;  // 1/sqrt(128)
    float pm[2][4];
    #pragma unroll
    for (int n2 = 0; n2 < 2; n2++)
      #pragma unroll
      for (int r = 0; r < 4; r++){
        float v = st[n2][r] * sc;
        int qrow2 = q0w + ((lane >> 4) << 2) + r;
        int kvc   = kv0 + n2*16 + (lane & 15);
        pm[n2][r] = (kvc > qrow2) ? -1e30f : v;
      }
    float mt[4], mnew[4], al[4], rs[4];
    #pragma unroll
    for (int r = 0; r < 4; r++) mt[r] = fmaxf(pm[0][r], pm[1][r]);
    #pragma unroll
    for (int mk = 1; mk < 16; mk <<= 1)
      #pragma unroll
      for (int r = 0; r < 4; r++) mt[r] = fmaxf(mt[r], __shfl_xor(mt[r], mk));
    #pragma unroll
    for (int r = 0; r < 4; r++){
      mnew[r] = fmaxf(mrow[r], mt[r]);
      al[r]   = __expf(mrow[r] - mnew[r]);
    }
    unsigned short* pw = &Plds[w][0];
    #pragma unroll
    for (int r = 0; r < 4; r++){
      float p0 = __expf(pm[0][r] - mnew[r]);
      float p1 = __expf(pm[1][r] - mnew[r]);
      rs[r] = p0 + p1;
      int qlr = ((lane >> 4) << 2) + r;
      pw[qlr*32 +      (lane & 15)] = f2b(p0);
      pw[qlr*32 + 16 + (lane & 15)] = f2b(p1);
    }
    #pragma unroll
    for (int mk = 1; mk < 16; mk <<= 1)
      #pragma unroll
      for (int r = 0; r < 4; r++) rs[r] += __shfl_xor(rs[r], mk);
    #pragma unroll
    for (int r = 0; r < 4; r++){
      lrow[r] = lrow[r]*al[r] + rs[r];
      mrow[r] = mnew[r];
    }
    #pragma unroll
    for (int c = 0; c < 8; c++)
      #pragma unroll
      for (int r = 0; r < 4; r++) o[c][r] *= al[r];

    asm volatile("s_waitcnt lgkmcnt(0)" ::: "memory");
    s16x8 pa = *(const s16x8*)((const char*)pw + (lane & 15)*64 + ((lane >> 4) << 4));
    #pragma unroll
    for (int c = 0; c < 8; c++){
      int d = c*16 + (lane & 15);
      s16x8 vf = *(const s16x8*)((const char*)Vlds + d*128 +
                   ((((lane >> 4) << 4)) ^ ((d & 7) << 4)));
      o[c] = mfma16(pa, vf, o[c]);
    }
  }

  const int b = bh >> 4, h = bh & 15;
  #pragma unroll
  for (int r = 0; r < 4; r++){
    float inv = 1.0f / lrow[r];
    int s2 = q0w + ((lane >> 4) << 2) + r;
    size_t base = ((size_t)(b*SEQ + s2)) * DM + h*HD;
    #pragma unroll
    for (int c = 0; c < 8; c++)
      attnout[base + c*16 + (lane & 15)] = f2b(o[c][r] * inv);
  }
}

// ---------------------------------------------------------------------------
extern "C" void kernel_launch(void* const* d_in, const int* in_sizes, int n_in,
                              void* d_out, int out_size, void* d_ws, size_t ws_size,
                              hipStream_t stream)
{
  const float* x  = (const float*)d_in[0];
  const float* wq = (const float*)d_in[1];
  const float* wk = (const float*)d_in[2];
  const float* wv = (const float*)d_in[3];
  const float* wo = (const float*)d_in[4];
  const int*   sp = (const int*)d_in[5];

  float* out  = (float*)d_out;            // (B,S,D) f32
  float* kout = out + 16777216;           // (B,H,S,hd) f32
  float* vout = out + 33554432;           // (B,H,S,hd) f32

  char* ws = (char*)d_ws;
  unsigned short* xb      = (unsigned short*)ws;                  // 8192x2048 bf16 (33.55MB)
  unsigned short* wfused  = (unsigned short*)(ws + 33554432);     // 6144x2048 bf16 (25.17MB)
  unsigned short* wob     = (unsigned short*)(ws + 58720256);     // 2048x2048 bf16 (8.39MB)
  unsigned short* qr      = (unsigned short*)(ws + 67108864);     // (B,H,S,hd) bf16
  unsigned short* kr      = (unsigned short*)(ws + 100663296);    // (B,H,S,hd) bf16
  unsigned short* vt      = (unsigned short*)(ws + 134217728);    // (B,H,hd,S) bf16
  unsigned short* attnout = (unsigned short*)ws;                  // alias xb (dead after GEMM1)

  // 1) f32 -> bf16 conversion of activations + weights
  convert_kernel<<<16384, 256, 0, stream>>>(x, wq, wk, wv, wo, xb, wfused, wob);
  // 2) fused QKV GEMM with RoPE epilogue
  gemm_kernel<0><<<dim3(64, 48), 256, 0, stream>>>(xb, wfused, qr, kr, kout,
                                                   vout, vt, nullptr, sp);
  // 3) causal flash attention
  attn_kernel<<<dim3(32, 64), 256, 0, stream>>>(qr, kr, vt, attnout);
  // 4) output GEMM
  gemm_kernel<1><<<dim3(64, 16), 256, 0, stream>>>(attnout, wob, nullptr, nullptr,
                                                   nullptr, nullptr, nullptr, out, nullptr);
}